// Round 1
// baseline (854.048 us; speedup 1.0000x reference)
//
#include <hip/hip_runtime.h>
#include <math.h>

#define BLOCK 64

// One thread per particle. RK4 in registers; only p_y is conserved exactly
// (B = [0,By,0] => dp_y/dt = 0) and the field depends only on z.
__global__ __launch_bounds__(BLOCK) void track_rk4(
    const float* __restrict__ r_in,
    const float* __restrict__ d_vec,
    const float* __restrict__ g_in,
    const float* __restrict__ t_in,
    const float* __restrict__ b_in,
    float* __restrict__ out,
    int N, int T)
{
    const int n = blockIdx.x * BLOCK + threadIdx.x;
    if (n >= N) return;

    const float c      = 0.299792458f;
    const float c2     = c * c;
    const float inv_c2 = 1.0f / c2;
    const float k_u    = 6.283185307179586f; // 2*pi

    const float b0  = b_in[0];
    const float dt  = t_in[1] - t_in[0];
    const float dt2 = 0.5f * dt;
    const float dt6 = dt * (1.0f / 6.0f);

    float rx = r_in[3*n+0], ry = r_in[3*n+1], rz = r_in[3*n+2];
    const float dx = d_vec[3*n+0], dy = d_vec[3*n+1], dz = d_vec[3*n+2];
    const float g0 = g_in[n];

    // p0 = c*sqrt(g^2-1) * d / |d|
    const float pscale = c * sqrtf(g0*g0 - 1.0f)
                       * rsqrtf(fmaf(dx,dx, fmaf(dy,dy, dz*dz)));
    float px = dx * pscale;
    const float py = dy * pscale;   // constant for all time
    float pz = dz * pscale;

    // out[((q*N + n)*3 + c)*T + t]
    const long Tl = (long)T;
    float* __restrict__ orx = out + (3L*n + 0) * Tl;
    float* __restrict__ ory = out + (3L*n + 1) * Tl;
    float* __restrict__ orz = out + (3L*n + 2) * Tl;
    const long boff = 3L * (long)N * Tl;   // offset to beta block

    const float py2 = py * py;

    // t = 0 output
    {
        float ib = rsqrtf(fmaf(px,px, fmaf(pz,pz, py2 + c2)));
        orx[0] = rx;            ory[0] = ry;            orz[0] = rz;
        orx[boff] = px * ib;    ory[boff] = py * ib;    orz[boff] = pz * ib;
    }

    for (int t = 1; t < T; ++t) {
        // ---- stage 1 (at r, p)
        float ig1  = rsqrtf(fmaf(fmaf(px,px, fmaf(pz,pz, py2)), inv_c2, 1.0f));
        float By1  = b0 * __cosf(k_u * rz);
        float rk1x = px*ig1, rk1z = pz*ig1;
        float h1   = By1 * ig1;
        float pk1x =  pz*h1, pk1z = -px*h1;

        // ---- stage 2
        float p2x = fmaf(pk1x, dt2, px);
        float p2z = fmaf(pk1z, dt2, pz);
        float z2  = fmaf(rk1z, dt2, rz);
        float ig2  = rsqrtf(fmaf(fmaf(p2x,p2x, fmaf(p2z,p2z, py2)), inv_c2, 1.0f));
        float By2  = b0 * __cosf(k_u * z2);
        float rk2x = p2x*ig2, rk2z = p2z*ig2;
        float h2   = By2 * ig2;
        float pk2x =  p2z*h2, pk2z = -p2x*h2;

        // ---- stage 3
        float p3x = fmaf(pk2x, dt2, px);
        float p3z = fmaf(pk2z, dt2, pz);
        float z3  = fmaf(rk2z, dt2, rz);
        float ig3  = rsqrtf(fmaf(fmaf(p3x,p3x, fmaf(p3z,p3z, py2)), inv_c2, 1.0f));
        float By3  = b0 * __cosf(k_u * z3);
        float rk3x = p3x*ig3, rk3z = p3z*ig3;
        float h3   = By3 * ig3;
        float pk3x =  p3z*h3, pk3z = -p3x*h3;

        // ---- stage 4
        float p4x = fmaf(pk3x, dt, px);
        float p4z = fmaf(pk3z, dt, pz);
        float z4  = fmaf(rk3z, dt, rz);
        float ig4  = rsqrtf(fmaf(fmaf(p4x,p4x, fmaf(p4z,p4z, py2)), inv_c2, 1.0f));
        float By4  = b0 * __cosf(k_u * z4);
        float rk4x = p4x*ig4, rk4z = p4z*ig4;
        float h4   = By4 * ig4;
        float pk4x =  p4z*h4, pk4z = -p4x*h4;

        // ---- combine
        float igsum = ig1 + 2.0f*ig2 + 2.0f*ig3 + ig4;   // for ry (rk_y = py*ig)
        rx = fmaf(dt6, rk1x + 2.0f*rk2x + 2.0f*rk3x + rk4x, rx);
        ry = fmaf(dt6, py * igsum, ry);
        rz = fmaf(dt6, rk1z + 2.0f*rk2z + 2.0f*rk3z + rk4z, rz);
        px = fmaf(dt6, pk1x + 2.0f*pk2x + 2.0f*pk3x + pk4x, px);
        pz = fmaf(dt6, pk1z + 2.0f*pk2z + 2.0f*pk3z + pk4z, pz);

        // ---- outputs
        float ib = rsqrtf(fmaf(px,px, fmaf(pz,pz, py2 + c2)));
        orx[t] = rx;             ory[t] = ry;             orz[t] = rz;
        orx[boff + t] = px * ib; ory[boff + t] = py * ib; orz[boff + t] = pz * ib;
    }
}

extern "C" void kernel_launch(void* const* d_in, const int* in_sizes, int n_in,
                              void* d_out, int out_size, void* d_ws, size_t ws_size,
                              hipStream_t stream) {
    const float* r  = (const float*)d_in[0];
    const float* d  = (const float*)d_in[1];
    const float* g  = (const float*)d_in[2];
    const float* tm = (const float*)d_in[3];
    const float* b0 = (const float*)d_in[4];
    float* out = (float*)d_out;

    const int N = in_sizes[2];   // bunch_gamma has N elements
    const int T = in_sizes[3];   // time has T elements

    const int blocks = (N + BLOCK - 1) / BLOCK;
    track_rk4<<<blocks, BLOCK, 0, stream>>>(r, d, g, tm, b0, out, N, T);
}